// Round 3
// baseline (421.385 us; speedup 1.0000x reference)
//
#include <hip/hip_runtime.h>
#include <hip/hip_bf16.h>

typedef __attribute__((ext_vector_type(8))) short short8;
typedef __attribute__((ext_vector_type(4))) float floatx4;

__device__ __forceinline__ float bf2f(ushort u) {
    return __uint_as_float(((unsigned int)u) << 16);
}
__device__ __forceinline__ ushort f2bf(float f) {
    unsigned int u = __float_as_uint(f);
    unsigned int r = (u + 0x7FFFu + ((u >> 16) & 1u)) >> 16;
    return (ushort)r;
}
// NaN-scrub + clamp: NaN -> -lim, +-inf -> +-lim (fminf/fmaxf return non-NaN operand)
__device__ __forceinline__ float scrub(float v, float lim) {
    return fminf(fmaxf(v, -lim), lim);
}

// Wave-uniform dtype probe on x (never modified): for bf16 N(0,1) data, even-index
// ushorts have exponent byte in [117,131] ~99% of the time; for fp32 data those are
// uniform mantissa bits (~6% in range). 32 samples, threshold 16 -> >10 sigma margin.
__device__ __forceinline__ bool detect_bf16(const ushort* __restrict__ probe) {
    const int lane = threadIdx.x & 63;
    ushort u = probe[(lane & 31) * 2];
    int e = (u >> 7) & 0xFF;
    bool pl = (e >= 117) && (e <= 131) && (lane < 32);
    return __popcll(__ballot(pl)) >= 16;
}

// ---------------------------------------------------------------------------
// LN1: input dtype detected (bf16 or fp32), output bf16. One block per row.
// ---------------------------------------------------------------------------
__global__ __launch_bounds__(256) void ln1_kernel(const void* __restrict__ xin,
                                                  const void* __restrict__ gin,
                                                  ushort* __restrict__ out,
                                                  const ushort* __restrict__ probe) {
    const bool ib = detect_bf16(probe);
    const int row = blockIdx.x;
    const int tid = threadIdx.x;

    float v0, v1, v2, v3, g0, g1, g2, g3;
    if (ib) {
        const ushort* xr = (const ushort*)xin + (size_t)row * 1024 + tid * 4;
        uint2 u = *(const uint2*)xr;
        v0 = bf2f((ushort)(u.x & 0xFFFF)); v1 = bf2f((ushort)(u.x >> 16));
        v2 = bf2f((ushort)(u.y & 0xFFFF)); v3 = bf2f((ushort)(u.y >> 16));
        uint2 gu = *(const uint2*)((const ushort*)gin + tid * 4);
        g0 = bf2f((ushort)(gu.x & 0xFFFF)); g1 = bf2f((ushort)(gu.x >> 16));
        g2 = bf2f((ushort)(gu.y & 0xFFFF)); g3 = bf2f((ushort)(gu.y >> 16));
    } else {
        const float* xr = (const float*)xin + (size_t)row * 1024 + tid * 4;
        float4 xv = *(const float4*)xr;
        v0 = xv.x; v1 = xv.y; v2 = xv.z; v3 = xv.w;
        float4 gv = *(const float4*)((const float*)gin + tid * 4);
        g0 = gv.x; g1 = gv.y; g2 = gv.z; g3 = gv.w;
    }
    v0 = scrub(v0, 1e8f); v1 = scrub(v1, 1e8f); v2 = scrub(v2, 1e8f); v3 = scrub(v3, 1e8f);
    g0 = scrub(g0, 1e8f); g1 = scrub(g1, 1e8f); g2 = scrub(g2, 1e8f); g3 = scrub(g3, 1e8f);

    float s  = v0 + v1 + v2 + v3;
    float sq = v0 * v0 + v1 * v1 + v2 * v2 + v3 * v3;
    #pragma unroll
    for (int off = 1; off < 64; off <<= 1) {
        s  += __shfl_xor(s, off);
        sq += __shfl_xor(sq, off);
    }
    __shared__ float red[8];
    const int w = tid >> 6, lane = tid & 63;
    if (lane == 0) { red[w] = s; red[w + 4] = sq; }
    __syncthreads();
    float S  = red[0] + red[1] + red[2] + red[3];
    float SQ = red[4] + red[5] + red[6] + red[7];

    float mean = S * (1.0f / 1024.0f);
    float var  = SQ * (1.0f / 1024.0f) - mean * mean;
    float rstd = rsqrtf(fmaxf(var, 0.0f) + 1e-5f);

    ushort o0 = f2bf((v0 - mean) * rstd * g0);
    ushort o1 = f2bf((v1 - mean) * rstd * g1);
    ushort o2 = f2bf((v2 - mean) * rstd * g2);
    ushort o3 = f2bf((v3 - mean) * rstd * g3);
    uint2 ov;
    ov.x = (unsigned int)o0 | ((unsigned int)o1 << 16);
    ov.y = (unsigned int)o2 | ((unsigned int)o3 << 16);
    *(uint2*)(out + (size_t)row * 1024 + tid * 4) = ov;
}

// ---------------------------------------------------------------------------
// LN2: input bf16 (our intermediate), gamma + OUTPUT dtype detected.
// ---------------------------------------------------------------------------
__global__ __launch_bounds__(256) void ln2_kernel(const ushort* __restrict__ y,
                                                  const void* __restrict__ gin,
                                                  void* __restrict__ out,
                                                  const ushort* __restrict__ probe) {
    const bool ob = detect_bf16(probe);
    const int row = blockIdx.x;
    const int tid = threadIdx.x;

    uint2 u = *(const uint2*)(y + (size_t)row * 1024 + tid * 4);
    float v0 = scrub(bf2f((ushort)(u.x & 0xFFFF)), 1e8f);
    float v1 = scrub(bf2f((ushort)(u.x >> 16)),    1e8f);
    float v2 = scrub(bf2f((ushort)(u.y & 0xFFFF)), 1e8f);
    float v3 = scrub(bf2f((ushort)(u.y >> 16)),    1e8f);

    float g0, g1, g2, g3;
    if (ob) {
        uint2 gu = *(const uint2*)((const ushort*)gin + tid * 4);
        g0 = bf2f((ushort)(gu.x & 0xFFFF)); g1 = bf2f((ushort)(gu.x >> 16));
        g2 = bf2f((ushort)(gu.y & 0xFFFF)); g3 = bf2f((ushort)(gu.y >> 16));
    } else {
        float4 gv = *(const float4*)((const float*)gin + tid * 4);
        g0 = gv.x; g1 = gv.y; g2 = gv.z; g3 = gv.w;
    }
    g0 = scrub(g0, 1e8f); g1 = scrub(g1, 1e8f); g2 = scrub(g2, 1e8f); g3 = scrub(g3, 1e8f);

    float s  = v0 + v1 + v2 + v3;
    float sq = v0 * v0 + v1 * v1 + v2 * v2 + v3 * v3;
    #pragma unroll
    for (int off = 1; off < 64; off <<= 1) {
        s  += __shfl_xor(s, off);
        sq += __shfl_xor(sq, off);
    }
    __shared__ float red[8];
    const int w = tid >> 6, lane = tid & 63;
    if (lane == 0) { red[w] = s; red[w + 4] = sq; }
    __syncthreads();
    float S  = red[0] + red[1] + red[2] + red[3];
    float SQ = red[4] + red[5] + red[6] + red[7];

    float mean = S * (1.0f / 1024.0f);
    float var  = SQ * (1.0f / 1024.0f) - mean * mean;
    float rstd = rsqrtf(fmaxf(var, 0.0f) + 1e-5f);

    float o0 = (v0 - mean) * rstd * g0;
    float o1 = (v1 - mean) * rstd * g1;
    float o2 = (v2 - mean) * rstd * g2;
    float o3 = (v3 - mean) * rstd * g3;
    if (ob) {
        uint2 ov;
        ov.x = (unsigned int)f2bf(o0) | ((unsigned int)f2bf(o1) << 16);
        ov.y = (unsigned int)f2bf(o2) | ((unsigned int)f2bf(o3) << 16);
        *(uint2*)((ushort*)out + (size_t)row * 1024 + tid * 4) = ov;
    } else {
        float4 ov = make_float4(o0, o1, o2, o3);
        *(float4*)((float*)out + (size_t)row * 1024 + tid * 4) = ov;
    }
}

// ---------------------------------------------------------------------------
// Transpose to bf16: input dtype detected unless force_bf16. out[c][r]=in[r][c].
// grid=(C/32, R/32, batch), block=256.
// ---------------------------------------------------------------------------
__global__ __launch_bounds__(256) void transpose_kernel(const void* __restrict__ in,
                                                        ushort* __restrict__ out,
                                                        int in_rs, long long in_bs,
                                                        int out_rs, long long out_bs,
                                                        int force_bf16,
                                                        const ushort* __restrict__ probe) {
    const bool ib = force_bf16 ? true : detect_bf16(probe);
    __shared__ ushort tile[32][33];
    const int tx = threadIdx.x & 31, ty = threadIdx.x >> 5;

    #pragma unroll
    for (int rr = 0; rr < 32; rr += 8) {
        size_t idx = (size_t)blockIdx.z * in_bs + (size_t)(blockIdx.y * 32 + ty + rr) * in_rs
                   + blockIdx.x * 32 + tx;
        float v = ib ? bf2f(((const ushort*)in)[idx]) : ((const float*)in)[idx];
        tile[ty + rr][tx] = f2bf(scrub(v, 1e8f));
    }
    __syncthreads();
    ushort* op = out + (size_t)blockIdx.z * out_bs;
    #pragma unroll
    for (int rr = 0; rr < 32; rr += 8) {
        int r = blockIdx.x * 32 + ty + rr;
        int c = blockIdx.y * 32 + tx;
        op[(size_t)r * out_rs + c] = tile[tx][ty + rr];
    }
}

// ---------------------------------------------------------------------------
// GEMM: C[M,N] = A[M,K] @ Bt[N,K]^T  (bf16 in/out, fp32 acc). Unchanged (audited).
// ---------------------------------------------------------------------------
__global__ __launch_bounds__(256) void gemm_bt(const ushort* __restrict__ A,
                                               const ushort* __restrict__ Bt,
                                               ushort* __restrict__ C,
                                               int M, int N, int K) {
    __shared__ ushort a_t[64][40];
    __shared__ ushort b_t[64][40];

    const int n0 = blockIdx.x * 64, m0 = blockIdx.y * 64;
    const int tid = threadIdx.x;
    const int w = tid >> 6, lane = tid & 63;
    const int fm = lane & 15, quad = lane >> 4;
    const int lrow = tid >> 2, lk = (tid & 3) * 8;

    const ushort* ag = A + (size_t)(m0 + lrow) * K + lk;
    const ushort* bg = Bt + (size_t)(n0 + lrow) * K + lk;

    floatx4 acc[4];
    floatx4 zero4 = {0.0f, 0.0f, 0.0f, 0.0f};
    #pragma unroll
    for (int nt = 0; nt < 4; nt++) acc[nt] = zero4;

    for (int k0 = 0; k0 < K; k0 += 32) {
        uint4 av = *(const uint4*)(ag + k0);
        uint4 bv = *(const uint4*)(bg + k0);
        __syncthreads();
        *(uint2*)&a_t[lrow][lk]     = make_uint2(av.x, av.y);
        *(uint2*)&a_t[lrow][lk + 4] = make_uint2(av.z, av.w);
        *(uint2*)&b_t[lrow][lk]     = make_uint2(bv.x, bv.y);
        *(uint2*)&b_t[lrow][lk + 4] = make_uint2(bv.z, bv.w);
        __syncthreads();

        union { uint2 u2[2]; short8 s8; } af;
        af.u2[0] = *(const uint2*)&a_t[w * 16 + fm][quad * 8];
        af.u2[1] = *(const uint2*)&a_t[w * 16 + fm][quad * 8 + 4];
        #pragma unroll
        for (int nt = 0; nt < 4; nt++) {
            union { uint2 u2[2]; short8 s8; } bf;
            bf.u2[0] = *(const uint2*)&b_t[nt * 16 + fm][quad * 8];
            bf.u2[1] = *(const uint2*)&b_t[nt * 16 + fm][quad * 8 + 4];
            acc[nt] = __builtin_amdgcn_mfma_f32_16x16x32_bf16(af.s8, bf.s8, acc[nt], 0, 0, 0);
        }
    }

    #pragma unroll
    for (int nt = 0; nt < 4; nt++)
        #pragma unroll
        for (int r = 0; r < 4; r++)
            C[(size_t)(m0 + w * 16 + quad * 4 + r) * N + n0 + nt * 16 + fm] = f2bf(acc[nt][r]);
}

// ---------------------------------------------------------------------------
// l2norm+scale: v <- 4 * v / max(||v||, 1e-12) over 64-elem vectors, scrubbed.
// ---------------------------------------------------------------------------
__global__ __launch_bounds__(256) void l2norm_kernel(ushort* __restrict__ q,
                                                     ushort* __restrict__ kv) {
    const int w = threadIdx.x >> 6, lane = threadIdx.x & 63;
    const int vec = blockIdx.x * 4 + w;
    ushort* p;
    if (vec < 65536) p = q + (size_t)vec * 64 + lane;
    else             p = kv + (size_t)(vec - 65536) * 128 + lane;
    float x = scrub(bf2f(*p), 1e15f);
    float ss = x * x;
    #pragma unroll
    for (int off = 1; off < 64; off <<= 1) ss += __shfl_xor(ss, off);
    float sc = 4.0f / fmaxf(sqrtf(ss), 1e-12f);
    *p = f2bf(x * sc);
}

// ---------------------------------------------------------------------------
// Flash attention, fixed softmax max = 16. Unchanged (audited + NaN-proof).
// ---------------------------------------------------------------------------
__global__ __launch_bounds__(256) void attn_kernel(const ushort* __restrict__ q,
                                                   const ushort* __restrict__ kv,
                                                   const ushort* __restrict__ vt,
                                                   ushort* __restrict__ out) {
    __shared__ ushort p_tile[4][16][72];

    const int i0 = blockIdx.x * 64;
    const int h = blockIdx.y, b = blockIdx.z;
    const int tid = threadIdx.x, w = tid >> 6, lane = tid & 63;
    const int fm = lane & 15, quad = lane >> 4;

    union U8 { uint4 u4; short8 s8; };

    const ushort* qbase = q + ((size_t)(b * 2048 + i0 + w * 16 + fm) * 512) + h * 64 + quad * 8;
    U8 qf0, qf1;
    qf0.u4 = *(const uint4*)qbase;
    qf1.u4 = *(const uint4*)(qbase + 32);

    floatx4 zero4 = {0.0f, 0.0f, 0.0f, 0.0f};
    floatx4 acc_o[4];
    #pragma unroll
    for (int od = 0; od < 4; od++) acc_o[od] = zero4;
    float l[4] = {0.0f, 0.0f, 0.0f, 0.0f};

    const ushort* kvb = kv + (size_t)b * 2048 * 128;
    const ushort* vtb = vt + (size_t)b * 64 * 2048;

    for (int j0 = 0; j0 < 2048; j0 += 64) {
        floatx4 s[4];
        #pragma unroll
        for (int nt = 0; nt < 4; nt++) {
            const ushort* kr = kvb + (size_t)(j0 + nt * 16 + fm) * 128 + quad * 8;
            U8 kb0, kb1;
            kb0.u4 = *(const uint4*)kr;
            kb1.u4 = *(const uint4*)(kr + 32);
            floatx4 a = zero4;
            a = __builtin_amdgcn_mfma_f32_16x16x32_bf16(qf0.s8, kb0.s8, a, 0, 0, 0);
            a = __builtin_amdgcn_mfma_f32_16x16x32_bf16(qf1.s8, kb1.s8, a, 0, 0, 0);
            s[nt] = a;
        }

        float pv[4][4];
        float rs[4] = {0.0f, 0.0f, 0.0f, 0.0f};
        #pragma unroll
        for (int nt = 0; nt < 4; nt++)
            #pragma unroll
            for (int r = 0; r < 4; r++) {
                float sv = fminf(s[nt][r], 16.0f);   // NaN -> 16, legit <= 16
                float p = __expf(sv - 16.0f);
                pv[nt][r] = p;
                rs[r] += p;
            }
        #pragma unroll
        for (int r = 0; r < 4; r++) {
            #pragma unroll
            for (int off = 1; off < 16; off <<= 1) rs[r] += __shfl_xor(rs[r], off);
            l[r] += rs[r];
        }

        #pragma unroll
        for (int nt = 0; nt < 4; nt++)
            #pragma unroll
            for (int r = 0; r < 4; r++)
                p_tile[w][quad * 4 + r][nt * 16 + fm] = f2bf(pv[nt][r]);

        U8 pa0, pa1;
        pa0.u4 = *(const uint4*)&p_tile[w][fm][quad * 8];
        pa1.u4 = *(const uint4*)&p_tile[w][fm][32 + quad * 8];

        #pragma unroll
        for (int od = 0; od < 4; od++) {
            const ushort* vr = vtb + (size_t)(od * 16 + fm) * 2048 + j0 + quad * 8;
            U8 vb0, vb1;
            vb0.u4 = *(const uint4*)vr;
            vb1.u4 = *(const uint4*)(vr + 32);
            acc_o[od] = __builtin_amdgcn_mfma_f32_16x16x32_bf16(pa0.s8, vb0.s8, acc_o[od], 0, 0, 0);
            acc_o[od] = __builtin_amdgcn_mfma_f32_16x16x32_bf16(pa1.s8, vb1.s8, acc_o[od], 0, 0, 0);
        }
    }

    float li[4];
    #pragma unroll
    for (int r = 0; r < 4; r++) li[r] = 1.0f / fmaxf(l[r], 1e-30f);

    ushort* ob = out + (size_t)(b * 2048 + i0 + w * 16) * 512 + h * 64;
    #pragma unroll
    for (int od = 0; od < 4; od++)
        #pragma unroll
        for (int r = 0; r < 4; r++)
            ob[(size_t)(quad * 4 + r) * 512 + od * 16 + fm] = f2bf(acc_o[od][r] * li[r]);
}

// ---------------------------------------------------------------------------
// Memory plan (all intermediates bf16):
//   d_out bytes: [0:16MB) xn (dead after GEMM2) -> [0:8MB) ao, [8:16MB) woT
//   ws bytes:    [0:8MB) qb, [8:10MB) kvb, [10:11MB) wqT, [11:11.25MB) wkvT,
//                [11.25:12.25MB) vt; then y @ [0:16MB) over the dead region.
//   ws_size needed: 16MB (= bf16 output size).
// ---------------------------------------------------------------------------
extern "C" void kernel_launch(void* const* d_in, const int* in_sizes, int n_in,
                              void* d_out, int out_size, void* d_ws, size_t ws_size,
                              hipStream_t stream) {
    const void* x          = d_in[0];
    const void* norm_g     = d_in[1];
    const void* Wq         = d_in[2];
    const void* Wkv        = d_in[3];
    const void* Wout       = d_in[4];
    const void* out_norm_g = d_in[5];
    const ushort* probe = (const ushort*)d_in[0];
    ushort* ws = (ushort*)d_ws;

    const size_t M1 = 1024 * 1024 / 2;  // elems per MB (bf16)
    ushort* xn   = (ushort*)d_out;                       // d_out [0:16MB)
    ushort* ao   = (ushort*)d_out;                       // d_out [0:8MB)
    ushort* woT  = (ushort*)((char*)d_out + (8u << 20)); // d_out [8:16MB)
    ushort* qb   = ws;                                   // ws [0:8MB)
    ushort* kvb  = ws + 8 * M1;                          // ws [8:10MB)
    ushort* wqT  = ws + 10 * M1;                         // ws [10:11MB)
    ushort* wkvT = ws + 11 * M1;                         // ws [11:11.25MB)
    ushort* vt   = ws + 11 * M1 + M1 / 4;                // ws [11.25:12.25MB)
    ushort* y    = ws;                                   // ws [0:16MB), after attn

    // Weight transposes -> bf16 [N][K]
    transpose_kernel<<<dim3(16, 32, 1), 256, 0, stream>>>(Wq, wqT, 512, 0, 1024, 0, 0, probe);
    transpose_kernel<<<dim3(4, 32, 1), 256, 0, stream>>>(Wkv, wkvT, 128, 0, 1024, 0, 0, probe);

    // LN1 -> xn (d_out as scratch)
    ln1_kernel<<<8192, 256, 0, stream>>>(x, norm_g, xn, probe);

    // q = xn @ Wq ; kv = xn @ Wkv   [xn dead after]
    gemm_bt<<<dim3(8, 128), 256, 0, stream>>>(xn, wqT, qb, 8192, 512, 1024);
    gemm_bt<<<dim3(2, 128), 256, 0, stream>>>(xn, wkvT, kvb, 8192, 128, 1024);

    // Wout^T -> d_out[8:16MB) (xn dead now)
    transpose_kernel<<<dim3(32, 16, 1), 256, 0, stream>>>(Wout, woT, 1024, 0, 512, 0, 0, probe);

    // q,k -> 4 * unit vectors
    l2norm_kernel<<<(65536 + 8192) / 4, 256, 0, stream>>>(qb, kvb);

    // vt[b][d][j] = v[b][j][d]  (bf16 input, force)
    transpose_kernel<<<dim3(2, 64, 4), 256, 0, stream>>>(
        kvb + 64, vt, 128, (long long)2048 * 128, 2048, (long long)64 * 2048, 1, probe);

    // attention -> ao (d_out[0:8MB))
    attn_kernel<<<dim3(32, 8, 4), 256, 0, stream>>>(qb, kvb, vt, ao);

    // y = ao @ Wout -> ws[0:16MB) (qb/kvb/wqT/wkvT/vt all dead)
    gemm_bt<<<dim3(16, 128), 256, 0, stream>>>(ao, woT, y, 8192, 1024, 512);

    // LN2: y -> final output (dtype-detected store)
    ln2_kernel<<<8192, 256, 0, stream>>>(y, out_norm_g, d_out, probe);
}